// Round 13
// baseline (58.503 us; speedup 1.0000x reference)
//
#include <hip/hip_runtime.h>
#include <cstddef>

#define L1n 128
#define L2n 256
#define Kn  1024
#define NSTEP 16            // K phases of BK=64

using frag_ab = __attribute__((ext_vector_type(8))) short;  // 8 bf16
using frag_cd = __attribute__((ext_vector_type(4))) float;  // 4 f32

typedef __attribute__((address_space(1))) const unsigned int gconst_u32;
typedef __attribute__((address_space(3))) unsigned int lds_u32;

// RNE f32->bf16 pair pack (low, high)
__device__ __forceinline__ unsigned pack_bf16(float x, float y) {
    unsigned ux = __float_as_uint(x);
    ux = (ux + 0x7FFFu + ((ux >> 16) & 1u)) >> 16;
    unsigned uy = __float_as_uint(y);
    uy = (uy + 0x7FFFu + ((uy >> 16) & 1u)) & 0xFFFF0000u;
    return ux | uy;
}
__device__ __forceinline__ float dot4(float4 v) {
    return v.x * v.x + v.y * v.y + v.z * v.z + v.w * v.w;
}
__device__ __forceinline__ frag_ab mk_frag(float4 a, float4 b) {
    union { frag_ab f; unsigned u[4]; } r;
    r.u[0] = pack_bf16(a.x, a.y);
    r.u[1] = pack_bf16(a.z, a.w);
    r.u[2] = pack_bf16(b.x, b.y);
    r.u[3] = pack_bf16(b.z, b.w);
    return r.f;
}

// ---------------- Kernel 1: gload_lds-staged fused GEMM + norms + dist ----------------
// 512 blocks x 256 thr (64x64 tile, BK=64, 16 phases) -- the only shell that
// sustains full-chip demand BW. Staging now = global_load_lds width-16 of RAW
// f32 (m97 structure: 52 GB/s/CU measured vs our reg-staged 26): no VGPR
// round-trip, no ds_write, no staging-side pack. LDS stays LINEAR (gload_lds
// requirement); bank conflicts fixed by pre-swizzling the GLOBAL source with
// the involution off ^= (row&7)<<4 and applying the same XOR on ds_read
// (rule #21). bf16 conversion + row/col sum-of-squares happen at fragment-
// read time; each wave self-contains the norms it needs (shfl reduce), so
// the sInv LDS staging + extra barrier are gone.
__global__ __launch_bounds__(256) void gemm_dist_kernel(
    const float* __restrict__ seq1,
    const float* __restrict__ seq2,
    float* __restrict__ dist)
{
    __shared__ __align__(16) unsigned char sA[2][64 * 256];  // 64 rows x 256 B f32
    __shared__ __align__(16) unsigned char sB[2][64 * 256];  // (64 KB total)

    // bijective XCD-chunk swizzle (512 % 8 == 0)
    const int wg   = ((blockIdx.x & 7) << 6) + (blockIdx.x >> 3);
    const int b    = wg >> 3;
    const int mt   = (wg >> 2) & 1;
    const int nt   = wg & 3;
    const int t    = threadIdx.x;
    const int lane = t & 63;
    const int w    = t >> 6;
    const int wr   = w >> 1;     // A row-half of this wave's output
    const int wc   = w & 1;      // B col-half

    // ---- staging map: chunk c = i*256 + t; row = i*16 + (t>>4); ci = t&15 ----
    const int srow = t >> 4;                       // 0..15 base row
    const int gswz = (srow & 7) << 4;              // row&7 == (t>>4)&7 for all i
    const int goff = ((t & 15) << 4) ^ gswz;       // pre-swizzled source byte in slice
    const char* gA = (const char*)seq1 +
        ((size_t)b * L1n + mt * 64 + srow) * (Kn * 4) + goff;
    const char* gB = (const char*)seq2 +
        ((size_t)b * L2n + nt * 64 + srow) * (Kn * 4) + goff;
    const int ldsw = w * 1024;                     // wave-uniform lds sub-base

    auto stage = [&](int s, int buf) {
        const char* a = gA + (size_t)s * 256;
        const char* p = gB + (size_t)s * 256;
#pragma unroll
        for (int i = 0; i < 4; ++i) {
            __builtin_amdgcn_global_load_lds(
                (gconst_u32*)(a + i * 65536),
                (lds_u32*)(&sA[buf][i * 4096 + ldsw]), 16, 0, 0);
            __builtin_amdgcn_global_load_lds(
                (gconst_u32*)(p + i * 65536),
                (lds_u32*)(&sB[buf][i * 4096 + ldsw]), 16, 0, 0);
        }
    };

    // ---- consumer state ----
    frag_cd acc[2][2] = {};        // [nj][mi], operand-swapped: reg-dim = seq2 col
    float ssA[2] = {}, ssB[2] = {};
    const int lswz = (lane & 7) << 4;              // rowm&7 == lane&7
    const int g32  = (lane >> 4) << 5;             // k-window byte offset (8 f32)
    const int rA0  = wr * 32 + (lane & 15);        // A rows rA0, rA0+16
    const int rB0  = wc * 32 + (lane & 15);        // B cols rB0, rB0+16

    auto consume = [&](int buf) {
        frag_ab aF[2][2], bF[2][2];
#pragma unroll
        for (int kk = 0; kk < 2; ++kk) {
            const int o0 = (kk * 128 + g32) ^ lswz;
            const int o1 = (kk * 128 + g32 + 16) ^ lswz;
#pragma unroll
            for (int mi = 0; mi < 2; ++mi) {
                const unsigned char* p = &sA[buf][(rA0 + mi * 16) * 256];
                float4 lo = *reinterpret_cast<const float4*>(p + o0);
                float4 hi = *reinterpret_cast<const float4*>(p + o1);
                ssA[mi] += dot4(lo) + dot4(hi);
                aF[mi][kk] = mk_frag(lo, hi);
            }
#pragma unroll
            for (int nj = 0; nj < 2; ++nj) {
                const unsigned char* p = &sB[buf][(rB0 + nj * 16) * 256];
                float4 lo = *reinterpret_cast<const float4*>(p + o0);
                float4 hi = *reinterpret_cast<const float4*>(p + o1);
                ssB[nj] += dot4(lo) + dot4(hi);
                bF[nj][kk] = mk_frag(lo, hi);
            }
        }
#pragma unroll
        for (int kk = 0; kk < 2; ++kk)
#pragma unroll
            for (int nj = 0; nj < 2; ++nj)
#pragma unroll
                for (int mi = 0; mi < 2; ++mi)
                    acc[nj][mi] = __builtin_amdgcn_mfma_f32_16x16x32_bf16(
                        bF[nj][kk], aF[mi][kk], acc[nj][mi], 0, 0, 0);
    };

    // ---- m97 schedule: barrier drains stage s; then issue s+1; consume s ----
    stage(0, 0);
    for (int s = 0; s < NSTEP; ++s) {
        __syncthreads();                       // vmcnt(0) drain: buf[s&1] ready
        if (s + 1 < NSTEP) stage(s + 1, (s + 1) & 1);   // flies during consume
        consume(s & 1);
    }

    // ---- norms: each lane's k-window covers 1/4 of its rows; reduce over g ----
#pragma unroll
    for (int i = 0; i < 2; ++i) {
        ssA[i] += __shfl_xor(ssA[i], 16); ssA[i] += __shfl_xor(ssA[i], 32);
        ssB[i] += __shfl_xor(ssB[i], 16); ssB[i] += __shfl_xor(ssB[i], 32);
    }
    const float iA0 = rsqrtf(ssA[0]), iA1 = rsqrtf(ssA[1]);
    const float iB0 = rsqrtf(ssB[0]), iB1 = rsqrtf(ssB[1]);

    // ---- epilogue: dist_t[b][col][row] = 1 - acc*invA*invB (coalesced) ----
    float* dT = dist + (size_t)b * (L1n * L2n);
    const int csub = (lane >> 4) << 2;         // acc reg-dim col sub-offset
#pragma unroll
    for (int nj = 0; nj < 2; ++nj) {
        const float ibn = (nj == 0) ? iB0 : iB1;  (void)ibn;
        float ib[4];
#pragma unroll
        for (int x = 0; x < 4; ++x)
            ib[x] = __shfl((nj == 0) ? iB0 : iB1, csub + x);
#pragma unroll
        for (int mi = 0; mi < 2; ++mi) {
            const float ia = (mi == 0) ? iA0 : iA1;
            const int row = mt * 64 + wr * 32 + mi * 16 + (lane & 15);
            const int col = nt * 64 + wc * 32 + nj * 16 + csub;
#pragma unroll
            for (int x = 0; x < 4; ++x)
                dT[(size_t)(col + x) * L1n + row] =
                    1.0f - acc[nj][mi][x] * ia * ib[x];
        }
    }
}

// ---------------- Kernel 2: DTW lag-skewed column sweep, global-direct ----------------
// R4-proven (~2.4us): transposed dist_t[b][col][row], lane l owns rows 2l,2l+1,
// LAG=4 skew puts the shfl off the critical path; 16-deep float2 prefetch.
__global__ __launch_bounds__(64) void dtw_kernel(
    const float* __restrict__ dist, float* __restrict__ out)
{
    const int b    = blockIdx.x;
    const int lane = threadIdx.x;
    const float INF = 3.0e38f;
    const bool lane0 = (lane == 0);
    const float* base = dist + (size_t)b * (L1n * L2n) + 2 * lane;  // [col][row]

    float c0 = INF, c1 = INF;
    float sh0 = INF, sh1 = INF, sh2 = INF, sh3 = INF, sh4 = INF;

    auto ldval = [&](int tt) -> float2 {
        int jj = tt - 4 * lane;
        jj = jj < 0 ? 0 : (jj > L2n - 1 ? L2n - 1 : jj);
        return *reinterpret_cast<const float2*>(base + (size_t)jj * L1n);
    };

    auto step = [&](float2 d, bool t0) {
        float u = lane0 ? (t0 ? 0.0f : INF) : sh3;   // D(r0-1, jj)
        float g = lane0 ? INF : sh4;                  // D(r0-1, jj-1)
        float ugm = fminf(u, g);
        float n0 = d.x + fminf(c0, ugm);
        float n1 = d.y + fminf(fminf(c1, c0), n0);
        float snew = __shfl_up(n1, 1);
        sh4 = sh3; sh3 = sh2; sh2 = sh1; sh1 = sh0; sh0 = snew;
        c0 = n0; c1 = n1;
    };

    float2 pfA[8], pfB[8];
#pragma unroll
    for (int u = 0; u < 8; ++u) pfA[u] = ldval(u);
#pragma unroll
    for (int u = 0; u < 8; ++u) pfB[u] = ldval(8 + u);

#pragma unroll
    for (int u = 0; u < 8; ++u) step(pfA[u], u == 0);
#pragma unroll
    for (int u = 0; u < 8; ++u) pfA[u] = ldval(16 + u);

    int t = 8;
    for (int i = 0; i < 31; ++i) {    // t = 8 .. 503
        float2 curB[8];
#pragma unroll
        for (int u = 0; u < 8; ++u) curB[u] = pfB[u];
#pragma unroll
        for (int u = 0; u < 8; ++u) pfB[u] = ldval(t + 16 + u);
#pragma unroll
        for (int u = 0; u < 8; ++u) step(curB[u], false);

        float2 curA[8];
#pragma unroll
        for (int u = 0; u < 8; ++u) curA[u] = pfA[u];
#pragma unroll
        for (int u = 0; u < 8; ++u) pfA[u] = ldval(t + 24 + u);
#pragma unroll
        for (int u = 0; u < 8; ++u) step(curA[u], false);
        t += 16;
    }

#pragma unroll
    for (int u = 0; u < 4; ++u) step(pfB[u], false);

    // lane 63 finished (127,255) at t=507 -> c1
    if (lane == 63)
        out[b] = 1.0f / (1.0f + c1 * (1.0f / (float)(L1n + L2n)));
}

extern "C" void kernel_launch(void* const* d_in, const int* in_sizes, int n_in,
                              void* d_out, int out_size, void* d_ws, size_t ws_size,
                              hipStream_t stream) {
    const float* seq1 = (const float*)d_in[0];   // 64*128*1024 f32
    const float* seq2 = (const float*)d_in[1];   // 64*256*1024 f32
    float* out  = (float*)d_out;                 // 64 f32
    float* dist = (float*)d_ws;                  // 8 MB scratch (transposed dist)

    gemm_dist_kernel<<<dim3(512), dim3(256), 0, stream>>>(seq1, seq2, dist);
    dtw_kernel<<<dim3(64), dim3(64), 0, stream>>>(dist, out);
}